// Round 28
// baseline (186.475 us; speedup 1.0000x reference)
//
#include <hip/hip_runtime.h>
#include <stdint.h>

// ---------- problem constants ----------
#define S_LEN   2048
#define D_MODEL 2048
#define NH      32
#define NKV     8
#define HDIM    64
#define WIN     1024
#define QKV_N   3072
#define MTOT    4096          // B*S
#define QSCALE  0.18033688011112042f   // 0.125 * log2(e)

typedef __bf16 bf16x8 __attribute__((ext_vector_type(8)));
typedef float  f32x4  __attribute__((ext_vector_type(4)));
typedef unsigned short u16x8 __attribute__((ext_vector_type(8)));
typedef unsigned short u16x4 __attribute__((ext_vector_type(4)));

#define GLDS16(g, l) __builtin_amdgcn_global_load_lds( \
    (__attribute__((address_space(1))) void*)(g),      \
    (__attribute__((address_space(3))) void*)(l), 16, 0, 0)

// single-instruction v_exp_f32 (libm exp2f lowers to a multi-op ocml call)
#define EXP2(x) __builtin_amdgcn_exp2f(x)

// guarantee all outstanding DMA (global_load_lds) is complete before the
// barrier, independent of the compiler's barrier lowering. Closed the
// stochastic staging race of rounds 18-23 (r24-r27 verified: bit-stable).
#define VMDRAIN() asm volatile("s_waitcnt vmcnt(0)" ::: "memory")

// RNE f32->bf16 via the compiler cast (v_cvt_pk fusion).
__device__ __forceinline__ unsigned short f2bf(float f) {
  __bf16 b = (__bf16)f;
  return __builtin_bit_cast(unsigned short, b);
}

// ---------- fp32 -> bf16 conversion (weights only; x is fused into gemm1) ----------
__global__ void cvt3(const float* __restrict__ s0, unsigned short* __restrict__ d0, int n0,
                     const float* __restrict__ s1, unsigned short* __restrict__ d1, int n1,
                     const float* __restrict__ s2, unsigned short* __restrict__ d2, int n2)
{
  int total4 = (n0 + n1 + n2) >> 2;
  for (int idx = blockIdx.x * blockDim.x + threadIdx.x; idx < total4;
       idx += gridDim.x * blockDim.x) {
    int i = idx << 2;
    const float* s; unsigned short* d;
    if (i < n0)            { s = s0 + i;            d = d0 + i; }
    else if (i < n0 + n1)  { s = s1 + (i - n0);     d = d1 + (i - n0); }
    else                   { s = s2 + (i - n0 - n1); d = d2 + (i - n0 - n1); }
    float4 v = *(const float4*)s;
    u16x4 o;
    o[0] = f2bf(v.x); o[1] = f2bf(v.y); o[2] = f2bf(v.z); o[3] = f2bf(v.w);
    *(u16x4*)d = o;
  }
}

// ---------- NT GEMM: C[m,n] = sum_k A[m,k]*B[n,k] (+bias) ----------
// Round 28: BK=64 (r27-verified) + fused A conversion for EP==0.
// EP==0: A is FP32 (x) reg-staged (2x float4 load pre-swizzled source,
//   4x v_cvt_pk, ds_write_b128 to the identical linear dest byte the GLDS
//   path wrote -> bit-identical LDS image); B (bf16 weights) via GLDS.
//   Saves the cvt3 x round-trip (~50 MB HBM). r1-family reg-staging:
//   ds_writes drained by __syncthreads' lgkmcnt; VMDRAIN covers B DMA.
// EP==1: both operands bf16 via GLDS (unchanged r27 path).
// Tile [128 rows][64 k] bf16 = natural 128B rows; position p of row r holds
// source granule p^(r&7); reads use granule q=(4*h2+fq) at q^(r&7) ->
// conflict-free. Epilogue: QKV scatter via per-wave LDS transpose (EP0),
// fp32 out (EP1).
template<int EP>
__global__ __launch_bounds__(256)
void gemm_nt(const void* __restrict__ Ap, const unsigned short* __restrict__ Bm,
             const float* __restrict__ bias, int K, int N,
             unsigned short* __restrict__ qo, unsigned short* __restrict__ ko,
             unsigned short* __restrict__ vo, float* __restrict__ co)
{
  __shared__ __align__(16) char smem[(EP == 0) ? 36864 : 32768];
  char* sA = smem;                        // [128][64] bf16, swizzled rows
  char* sB = smem + 16384;

  const int t = threadIdx.x;
  const int l = t & 63;
  const int brow = blockIdx.y << 7;
  const int bcol = blockIdx.x << 7;
  const int wr = ((t >> 7) & 1) << 6;
  const int wc = ((t >> 6) & 1) << 6;

  // staging: thread t stages granules g = 256j + t (j=0..3) per matrix.
  // g -> row = 32j + (t>>3), pos = t&7; source granule sp = pos ^ (row&7)
  // (32j = 0 mod 8 -> sp is j-independent). Dest byte = j*4096 + t*16.
  const int g_swz = (t & 7) ^ ((t >> 3) & 7);
  const float* aF = nullptr;
  const unsigned short* aB = nullptr;
  if constexpr (EP == 0)
    aF = (const float*)Ap + (size_t)(brow + (t >> 3)) * K + (g_swz << 3);
  else
    aB = (const unsigned short*)Ap + (size_t)(brow + (t >> 3)) * K + (g_swz << 3);
  const unsigned short* bB = Bm + (size_t)(bcol + (t >> 3)) * K + (g_swz << 3);
  const size_t rowskip = (size_t)32 * K;
  char* ldsAw = sA + ((t >> 6) << 10);    // wave-uniform dest base (GLDS path)
  char* ldsBw = sB + ((t >> 6) << 10);

  f32x4 acc[4][4] = {};
  const int fr = l & 15;
  const int fq = l >> 4;

  for (int kt = 0; kt < K; kt += 64) {
    if constexpr (EP == 0) {
      // B via async DMA first (overlaps with A's reg staging)
#pragma unroll
      for (int j = 0; j < 4; ++j)
        GLDS16(bB + j * rowskip, ldsBw + (j << 12));
      // A: fp32 load (pre-swizzled source) -> bf16 -> linear ds_write
#pragma unroll
      for (int j = 0; j < 4; ++j) {
        const float4 v0 = *(const float4*)(aF + j * rowskip);
        const float4 v1 = *(const float4*)(aF + j * rowskip + 4);
        u16x8 c;
        c[0] = f2bf(v0.x); c[1] = f2bf(v0.y); c[2] = f2bf(v0.z); c[3] = f2bf(v0.w);
        c[4] = f2bf(v1.x); c[5] = f2bf(v1.y); c[6] = f2bf(v1.z); c[7] = f2bf(v1.w);
        *(u16x8*)(sA + (j << 12) + (t << 4)) = c;
      }
      aF += 64;
    } else {
#pragma unroll
      for (int j = 0; j < 4; ++j) {
        GLDS16(aB + j * rowskip, ldsAw + (j << 12));
        GLDS16(bB + j * rowskip, ldsBw + (j << 12));
      }
      aB += 64;
    }
    bB += 64;
    VMDRAIN();
    __syncthreads();

#pragma unroll
    for (int h2 = 0; h2 < 2; ++h2) {
      bf16x8 af[4], bf[4];
#pragma unroll
      for (int mi = 0; mi < 4; ++mi) {
        const int row = wr + mi * 16 + fr;
        af[mi] = *(const bf16x8*)(sA + (row << 7) +
            ((((h2 << 2) + fq) ^ (row & 7)) << 4));
      }
#pragma unroll
      for (int ni = 0; ni < 4; ++ni) {
        const int row = wc + ni * 16 + fr;
        bf[ni] = *(const bf16x8*)(sB + (row << 7) +
            ((((h2 << 2) + fq) ^ (row & 7)) << 4));
      }
#pragma unroll
      for (int mi = 0; mi < 4; ++mi)
#pragma unroll
        for (int ni = 0; ni < 4; ++ni)
          acc[mi][ni] = __builtin_amdgcn_mfma_f32_16x16x32_bf16(af[mi], bf[ni], acc[mi][ni], 0, 0, 0);
    }
    __syncthreads();   // final sync: all LDS reads done -> smem reusable
  }

  const int fq4 = fq << 2;
  if (EP == 0) {
    const int w2 = t >> 6;
    const int e0 = bcol + wc;            // wave's 64-aligned e-range (one head)
    const int m0 = brow + wr;
    const int bidx = m0 >> 11, s0 = m0 & 2047;
    unsigned short* tile = (unsigned short*)smem + w2 * (64 * 72);
    const float sc = (e0 < 2048) ? QSCALE : 1.0f;
    const bool isV = (e0 >= 2560);
#pragma unroll
    for (int ni = 0; ni < 4; ++ni) {
      const int dd = ni * 16 + fr;
      const float bs = bias[e0 + dd];
#pragma unroll
      for (int mi = 0; mi < 4; ++mi)
#pragma unroll
        for (int j = 0; j < 4; ++j) {
          const int mm = mi * 16 + fq4 + j;
          const float v = (acc[mi][ni][j] + bs) * sc;
          if (isV) tile[dd * 72 + mm] = f2bf(v);   // V: [d][m] (transposed)
          else     tile[mm * 72 + dd] = f2bf(v);   // Q/K: [m][d]
        }
    }
    const int lr = l >> 3, lc = l & 7;
    unsigned short* gbase;
    size_t rstride;
    if (e0 < 2048) {
      gbase = qo + (((size_t)bidx * NH + (e0 >> 6)) * S_LEN + s0) * HDIM;
      rstride = HDIM;
    } else if (e0 < 2560) {
      gbase = ko + (((size_t)bidx * NKV + ((e0 - 2048) >> 6)) * S_LEN + s0) * HDIM;
      rstride = HDIM;
    } else {
      gbase = vo + (((size_t)bidx * NKV + ((e0 - 2560) >> 6)) * HDIM) * (size_t)S_LEN + s0;
      rstride = S_LEN;
    }
#pragma unroll
    for (int p = 0; p < 8; ++p) {
      const int row = p * 8 + lr;
      u16x8 vv = *(const u16x8*)&tile[row * 72 + lc * 8];
      *(u16x8*)(gbase + (size_t)row * rstride + lc * 8) = vv;
    }
  } else {
#pragma unroll
    for (int mi = 0; mi < 4; ++mi)
#pragma unroll
      for (int j = 0; j < 4; ++j) {
        const int m = brow + wr + mi * 16 + fq4 + j;
#pragma unroll
        for (int ni = 0; ni < 4; ++ni) {
          const int n = bcol + wc + ni * 16 + fr;
          co[(size_t)m * N + n] = acc[mi][ni][j] + bias[n];
        }
      }
  }
}

// ---------- sliding-window flash attention, v13 + VMDRAIN (r25-r27 verified) ----------
// Fixed-shift softmax (m=0): exact by shift-invariance (Q pre-scaled by
// 0.125*log2e -> |S| <~ 26 in exp2 domain; masked scores exp2(-1e30)=0).
__global__ __launch_bounds__(512)
void attn_swin(const unsigned short* __restrict__ Qs, const unsigned short* __restrict__ Kb,
               const unsigned short* __restrict__ Vtb, unsigned short* __restrict__ ctx)
{
  __shared__ char lds[32768];   // 2 buffers x (K 8KB + V 8KB); merge reuses it

  const int t = threadIdx.x, w = t >> 6, l = t & 63;
  const int fr = l & 15, fq = l >> 4;
  const int qh = w & 3, kh = w >> 2;
  const int q0 = blockIdx.x << 6;
  const int h = blockIdx.y, b = blockIdx.z;
  const int g = h >> 2;

  const unsigned short* qp = Qs + (((size_t)(b * NH + h)) * S_LEN + q0 + (qh << 4)) * HDIM;
  const bf16x8 qf0 = *(const bf16x8*)(qp + fr * HDIM + (fq << 3));
  const bf16x8 qf1 = *(const bf16x8*)(qp + fr * HDIM + 32 + (fq << 3));

  const unsigned short* Kg  = Kb  + ((size_t)(b * NKV + g)) * S_LEN * HDIM;  // [s][d]
  const unsigned short* Vtg = Vtb + ((size_t)(b * NKV + g)) * HDIM * S_LEN;  // [d][s]

  float l_part = 0.0f;          // per-lane denominator partial (q = fr)
  f32x4 o_acc[4] = {};

  int lo = q0 - (WIN - 1); if (lo < 0) lo = 0; lo &= ~63;
  const int hi = q0 + 64;
  const int full_lo = q0 - (WIN - 64);
  const int full_hi = q0 - 64;

  const unsigned short* src0;
  const unsigned short* src1;
  {
    const int x0 = ((w & 3) << 11) + (l << 4);
    const int x1 = x0 + 1024;
    if (w < 4) {
      const int s0 = x0 >> 7, o0 = ((x0 >> 4) & 7) ^ (s0 & 7);
      const int s1 = x1 >> 7, o1 = ((x1 >> 4) & 7) ^ (s1 & 7);
      const int p0 = ((s0 >> 5) << 5) | (((s0 >> 2) & 3) << 3) | (((s0 >> 4) & 1) << 2) | (s0 & 3);
      const int p1 = ((s1 >> 5) << 5) | (((s1 >> 2) & 3) << 3) | (((s1 >> 4) & 1) << 2) | (s1 & 3);
      src0 = Kg + (size_t)(lo + p0) * HDIM + (o0 << 3);
      src1 = Kg + (size_t)(lo + p1) * HDIM + (o1 << 3);
    } else {
      const int d0 = x0 >> 7, o0 = ((x0 >> 4) & 7) ^ (d0 & 7);
      const int d1 = x1 >> 7, o1 = ((x1 >> 4) & 7) ^ (d1 & 7);
      src0 = Vtg + (size_t)d0 * S_LEN + lo + (o0 << 3);
      src1 = Vtg + (size_t)d1 * S_LEN + lo + (o1 << 3);
    }
  }
  const int sadv = (w < 4) ? 64 * HDIM : 64;
  const int dbase = ((w < 4) ? 0 : 8192) + ((w & 3) << 11) + (l << 4);

  char* bufA = lds;
  char* bufB = lds + 16384;

  GLDS16(src0, bufA + dbase);
  GLDS16(src1, bufA + dbase + 1024);
  src0 += sadv; src1 += sadv;

  const int iq = q0 + (qh << 4) + fr;
  const int swr = (fr & 7) << 4;

  auto TILE = [&](int kv0, const char* sK, const char* sV, bool MASKED)
      __attribute__((always_inline)) {
    bf16x8 kf[2][2];
#pragma unroll
    for (int ntg = 0; ntg < 2; ++ntg) {
      const int slot = (kh << 5) + (ntg << 4) + fr;
      kf[ntg][0] = *(const bf16x8*)(sK + (((slot << 7) + (fq << 4)) ^ swr));
      kf[ntg][1] = *(const bf16x8*)(sK + (((slot << 7) + ((fq + 4) << 4)) ^ swr));
    }
    __builtin_amdgcn_s_setprio(1);
    f32x4 sf[2];
#pragma unroll
    for (int ntg = 0; ntg < 2; ++ntg) {
      f32x4 z = {};
      z = __builtin_amdgcn_mfma_f32_16x16x32_bf16(kf[ntg][0], qf0, z, 0, 0, 0);
      z = __builtin_amdgcn_mfma_f32_16x16x32_bf16(kf[ntg][1], qf1, z, 0, 0, 0);
      sf[ntg] = z;
    }
    __builtin_amdgcn_s_setprio(0);
    if (MASKED) {
#pragma unroll
      for (int ntg = 0; ntg < 2; ++ntg)
#pragma unroll
        for (int r = 0; r < 4; ++r) {
          const int jk = kv0 + (kh << 5) + (fq << 3) + (ntg << 2) + r;
          if (jk > iq || jk <= iq - WIN) sf[ntg][r] = -1e30f;
        }
    }
    // ---- P = exp2(S) (fixed shift m=0); pack in-register as PV A-frag ----
    union { unsigned short us[8]; bf16x8 v; } pu;
    float lloc = 0.0f;
#pragma unroll
    for (int ntg = 0; ntg < 2; ++ntg)
#pragma unroll
      for (int r = 0; r < 4; ++r) {
        const float p = EXP2(sf[ntg][r]);
        lloc += p;
        pu.us[(ntg << 2) + r] = f2bf(p);
      }
    l_part += lloc;
    bf16x8 vf[4];
#pragma unroll
    for (int dt = 0; dt < 4; ++dt) {
      const int d = (dt << 4) + fr;
      vf[dt] = *(const bf16x8*)(sV + ((d << 7) + ((((kh << 2) + fq) ^ (fr & 7)) << 4)));
    }
    __builtin_amdgcn_s_setprio(1);
#pragma unroll
    for (int dt = 0; dt < 4; ++dt)
      o_acc[dt] = __builtin_amdgcn_mfma_f32_16x16x32_bf16(pu.v, vf[dt], o_acc[dt], 0, 0, 0);
    __builtin_amdgcn_s_setprio(0);
  };

  for (int kv0 = lo; kv0 < hi; kv0 += 64) {
    VMDRAIN();
    __syncthreads();
    if (kv0 + 64 < hi) {
      GLDS16(src0, bufB + dbase);
      GLDS16(src1, bufB + dbase + 1024);
      src0 += sadv; src1 += sadv;
    }
    const bool masked = (kv0 < full_lo) || (kv0 > full_hi);
    if (masked) TILE(kv0, bufA, bufA + 8192, true);
    else        TILE(kv0, bufA, bufA + 8192, false);
    char* tmp = bufA; bufA = bufB; bufB = tmp;
  }

  // ---- epilogue: reduce l over fq lanes; merge kh halves (pure add) ----
  float lsum = l_part;
  lsum += __shfl_xor(lsum, 16);
  lsum += __shfl_xor(lsum, 32);

  VMDRAIN();
  __syncthreads();   // staging done; reuse lds as merge scratch
  if (w < 4) {       // kh=0 publish (o, l)
    char* ob = lds + ((w & 3) << 12);
#pragma unroll
    for (int dt = 0; dt < 4; ++dt)
      *(f32x4*)(ob + (dt << 10) + (l << 4)) = o_acc[dt];
    if (fq == 0)
      *(float*)(lds + 16384 + ((w & 3) << 7) + (fr << 2)) = lsum;
  }
  __syncthreads();
  if (w >= 4) {      // kh=1 merge + write ctx
    const char* ob = lds + ((w & 3) << 12);
    const float l_p = *(const float*)(lds + 16384 + ((w & 3) << 7) + (fr << 2));
    const float inv = 1.0f / (lsum + l_p);
    float al[4];
#pragma unroll
    for (int r = 0; r < 4; ++r) al[r] = __shfl(inv, (fq << 2) + r, 16);
    unsigned short* cp = ctx + ((size_t)(b * S_LEN + q0 + (qh << 4))) * D_MODEL + h * HDIM;
#pragma unroll
    for (int dt = 0; dt < 4; ++dt) {
      const f32x4 op = *(const f32x4*)(ob + (dt << 10) + (l << 4));
#pragma unroll
      for (int r = 0; r < 4; ++r) {
        const float of = (o_acc[dt][r] + op[r]) * al[r];
        cp[(size_t)((fq << 2) + r) * D_MODEL + (dt << 4) + fr] = f2bf(of);
      }
    }
  }
}

// ---------- launch ----------
extern "C" void kernel_launch(void* const* d_in, const int* in_sizes, int n_in,
                              void* d_out, int out_size, void* d_ws, size_t ws_size,
                              hipStream_t stream)
{
  const float* x    = (const float*)d_in[0];
  const float* Wqkv = (const float*)d_in[1];
  const float* bqkv = (const float*)d_in[2];
  const float* Wout = (const float*)d_in[3];
  const float* bout = (const float*)d_in[4];
  float* out = (float*)d_out;

  char* ws = (char*)d_ws;
  if (ws_size < 62914560u) return;

  unsigned short* ctx   = (unsigned short*)(ws);               // attn output
  unsigned short* wqkvb = (unsigned short*)(ws + 16777216);
  unsigned short* woutb = (unsigned short*)(ws + 29360128);
  unsigned short* Qs    = (unsigned short*)(ws + 37748736);
  unsigned short* Kbuf  = (unsigned short*)(ws + 54525952);
  unsigned short* Vtbuf = (unsigned short*)(ws + 58720256);    // [b][g][d][s]

  // weights only: x conversion is fused into gemm1's A staging
  cvt3<<<1024, 256, 0, stream>>>(Wqkv, wqkvb, QKV_N * D_MODEL,
                                 Wout, woutb, D_MODEL * D_MODEL,
                                 Wout, woutb, 0);

  gemm_nt<0><<<dim3(QKV_N / 128, MTOT / 128), 256, 0, stream>>>(
      x, wqkvb, bqkv, D_MODEL, QKV_N, Qs, Kbuf, Vtbuf, nullptr);

  attn_swin<<<dim3(S_LEN / 64, NH, 2), 512, 0, stream>>>(Qs, Kbuf, Vtbuf, ctx);

  gemm_nt<1><<<dim3(D_MODEL / 128, MTOT / 128), 256, 0, stream>>>(
      ctx, woutb, bout, D_MODEL, D_MODEL, nullptr, nullptr, nullptr, out);
}

// Round 29
// 181.795 us; speedup vs baseline: 1.0257x; 1.0257x over previous
//
#include <hip/hip_runtime.h>
#include <stdint.h>

// ---------- problem constants ----------
#define S_LEN   2048
#define D_MODEL 2048
#define NH      32
#define NKV     8
#define HDIM    64
#define WIN     1024
#define QKV_N   3072
#define MTOT    4096          // B*S
#define QSCALE  0.18033688011112042f   // 0.125 * log2(e)

typedef __bf16 bf16x8 __attribute__((ext_vector_type(8)));
typedef float  f32x4  __attribute__((ext_vector_type(4)));
typedef unsigned short u16x8 __attribute__((ext_vector_type(8)));
typedef unsigned short u16x4 __attribute__((ext_vector_type(4)));

#define GLDS16(g, l) __builtin_amdgcn_global_load_lds( \
    (__attribute__((address_space(1))) void*)(g),      \
    (__attribute__((address_space(3))) void*)(l), 16, 0, 0)

// single-instruction v_exp_f32 (libm exp2f lowers to a multi-op ocml call)
#define EXP2(x) __builtin_amdgcn_exp2f(x)

// guarantee all outstanding DMA (global_load_lds) is complete before the
// barrier, independent of the compiler's barrier lowering. Closed the
// stochastic staging race of rounds 18-23 (r24-r27 verified: bit-stable).
#define VMDRAIN() asm volatile("s_waitcnt vmcnt(0)" ::: "memory")

// RNE f32->bf16 via the compiler cast (v_cvt_pk fusion).
__device__ __forceinline__ unsigned short f2bf(float f) {
  __bf16 b = (__bf16)f;
  return __builtin_bit_cast(unsigned short, b);
}

// ---------- fp32 -> bf16 conversion ----------
__global__ void cvt3(const float* __restrict__ s0, unsigned short* __restrict__ d0, int n0,
                     const float* __restrict__ s1, unsigned short* __restrict__ d1, int n1,
                     const float* __restrict__ s2, unsigned short* __restrict__ d2, int n2)
{
  int total4 = (n0 + n1 + n2) >> 2;
  for (int idx = blockIdx.x * blockDim.x + threadIdx.x; idx < total4;
       idx += gridDim.x * blockDim.x) {
    int i = idx << 2;
    const float* s; unsigned short* d;
    if (i < n0)            { s = s0 + i;            d = d0 + i; }
    else if (i < n0 + n1)  { s = s1 + (i - n0);     d = d1 + (i - n0); }
    else                   { s = s2 + (i - n0 - n1); d = d2 + (i - n0 - n1); }
    float4 v = *(const float4*)s;
    u16x4 o;
    o[0] = f2bf(v.x); o[1] = f2bf(v.y); o[2] = f2bf(v.z); o[3] = f2bf(v.w);
    *(u16x4*)d = o;
  }
}

// ---------- NT GEMM: C[m,n] = sum_k A[m,k]*B[n,k] (+bias) ----------
// r27-verified: BK=64 K-step, VMDRAIN-hardened sync, per-row granule
// swizzle. Tile [128 rows][64 k] bf16 = natural 128B rows; position p of
// row r holds source granule p^(r&7) (linear GLDS dest, pre-swizzled
// source); reads use granule q=(4*h2+fq) at q^(r&7) -> conflict-free.
// NOTE r28: fusing the fp32->bf16 x-conversion into A staging regressed
// (fp32 A doubles the panel-reuse fetch footprint: FETCH 72->153 MB) —
// keep A as pre-converted bf16.
// EP==0: QKV epilogue via per-wave LDS transpose. EP==1: fp32 out.
template<int EP>
__global__ __launch_bounds__(256)
void gemm_nt(const unsigned short* __restrict__ A, const unsigned short* __restrict__ Bm,
             const float* __restrict__ bias, int K, int N,
             unsigned short* __restrict__ qo, unsigned short* __restrict__ ko,
             unsigned short* __restrict__ vo, float* __restrict__ co)
{
  __shared__ __align__(16) char smem[(EP == 0) ? 36864 : 32768];
  char* sA = smem;                        // [128][64] bf16, swizzled rows
  char* sB = smem + 16384;

  const int t = threadIdx.x;
  const int l = t & 63;
  const int brow = blockIdx.y << 7;
  const int bcol = blockIdx.x << 7;
  const int wr = ((t >> 7) & 1) << 6;
  const int wc = ((t >> 6) & 1) << 6;

  // staging: thread t stages granules g = 256j + t (j=0..3) per matrix.
  // g -> row = 32j + (t>>3), pos = t&7; source granule sp = pos ^ (row&7)
  // (32j = 0 mod 8 -> sp is j-independent). Dest byte = j*4096 + t*16
  // = linear (GLDS-compliant: wave-uniform base + lane*16).
  const int g_swz = (t & 7) ^ ((t >> 3) & 7);
  const unsigned short* aB = A + (size_t)(brow + (t >> 3)) * K + (g_swz << 3);
  const unsigned short* bB = Bm + (size_t)(bcol + (t >> 3)) * K + (g_swz << 3);
  const size_t rowskip = (size_t)32 * K;
  char* ldsAw = sA + ((t >> 6) << 10);    // wave-uniform dest base
  char* ldsBw = sB + ((t >> 6) << 10);

  f32x4 acc[4][4] = {};
  const int fr = l & 15;
  const int fq = l >> 4;

  for (int kt = 0; kt < K; kt += 64) {
#pragma unroll
    for (int j = 0; j < 4; ++j) {
      GLDS16(aB + j * rowskip, ldsAw + (j << 12));
      GLDS16(bB + j * rowskip, ldsBw + (j << 12));
    }
    aB += 64; bB += 64;
    VMDRAIN();
    __syncthreads();

#pragma unroll
    for (int h2 = 0; h2 < 2; ++h2) {
      bf16x8 af[4], bf[4];
#pragma unroll
      for (int mi = 0; mi < 4; ++mi) {
        const int row = wr + mi * 16 + fr;
        af[mi] = *(const bf16x8*)(sA + (row << 7) +
            ((((h2 << 2) + fq) ^ (row & 7)) << 4));
      }
#pragma unroll
      for (int ni = 0; ni < 4; ++ni) {
        const int row = wc + ni * 16 + fr;
        bf[ni] = *(const bf16x8*)(sB + (row << 7) +
            ((((h2 << 2) + fq) ^ (row & 7)) << 4));
      }
#pragma unroll
      for (int mi = 0; mi < 4; ++mi)
#pragma unroll
        for (int ni = 0; ni < 4; ++ni)
          acc[mi][ni] = __builtin_amdgcn_mfma_f32_16x16x32_bf16(af[mi], bf[ni], acc[mi][ni], 0, 0, 0);
    }
    __syncthreads();   // final sync: all LDS reads done -> smem reusable
  }

  const int fq4 = fq << 2;
  if (EP == 0) {
    const int w2 = t >> 6;
    const int e0 = bcol + wc;            // wave's 64-aligned e-range (one head)
    const int m0 = brow + wr;
    const int bidx = m0 >> 11, s0 = m0 & 2047;
    unsigned short* tile = (unsigned short*)smem + w2 * (64 * 72);
    const float sc = (e0 < 2048) ? QSCALE : 1.0f;
    const bool isV = (e0 >= 2560);
#pragma unroll
    for (int ni = 0; ni < 4; ++ni) {
      const int dd = ni * 16 + fr;
      const float bs = bias[e0 + dd];
#pragma unroll
      for (int mi = 0; mi < 4; ++mi)
#pragma unroll
        for (int j = 0; j < 4; ++j) {
          const int mm = mi * 16 + fq4 + j;
          const float v = (acc[mi][ni][j] + bs) * sc;
          if (isV) tile[dd * 72 + mm] = f2bf(v);   // V: [d][m] (transposed)
          else     tile[mm * 72 + dd] = f2bf(v);   // Q/K: [m][d]
        }
    }
    const int lr = l >> 3, lc = l & 7;
    unsigned short* gbase;
    size_t rstride;
    if (e0 < 2048) {
      gbase = qo + (((size_t)bidx * NH + (e0 >> 6)) * S_LEN + s0) * HDIM;
      rstride = HDIM;
    } else if (e0 < 2560) {
      gbase = ko + (((size_t)bidx * NKV + ((e0 - 2048) >> 6)) * S_LEN + s0) * HDIM;
      rstride = HDIM;
    } else {
      gbase = vo + (((size_t)bidx * NKV + ((e0 - 2560) >> 6)) * HDIM) * (size_t)S_LEN + s0;
      rstride = S_LEN;
    }
#pragma unroll
    for (int p = 0; p < 8; ++p) {
      const int row = p * 8 + lr;
      u16x8 vv = *(const u16x8*)&tile[row * 72 + lc * 8];
      *(u16x8*)(gbase + (size_t)row * rstride + lc * 8) = vv;
    }
  } else {
#pragma unroll
    for (int mi = 0; mi < 4; ++mi)
#pragma unroll
      for (int j = 0; j < 4; ++j) {
        const int m = brow + wr + mi * 16 + fq4 + j;
#pragma unroll
        for (int ni = 0; ni < 4; ++ni) {
          const int n = bcol + wc + ni * 16 + fr;
          co[(size_t)m * N + n] = acc[mi][ni][j] + bias[n];
        }
      }
  }
}

// ---------- sliding-window flash attention, v13 + VMDRAIN (r25-r27 verified) ----------
// Fixed-shift softmax (m=0): exact by shift-invariance (Q pre-scaled by
// 0.125*log2e -> |S| <~ 26 in exp2 domain; masked scores exp2(-1e30)=0).
__global__ __launch_bounds__(512)
void attn_swin(const unsigned short* __restrict__ Qs, const unsigned short* __restrict__ Kb,
               const unsigned short* __restrict__ Vtb, unsigned short* __restrict__ ctx)
{
  __shared__ char lds[32768];   // 2 buffers x (K 8KB + V 8KB); merge reuses it

  const int t = threadIdx.x, w = t >> 6, l = t & 63;
  const int fr = l & 15, fq = l >> 4;
  const int qh = w & 3, kh = w >> 2;
  const int q0 = blockIdx.x << 6;
  const int h = blockIdx.y, b = blockIdx.z;
  const int g = h >> 2;

  const unsigned short* qp = Qs + (((size_t)(b * NH + h)) * S_LEN + q0 + (qh << 4)) * HDIM;
  const bf16x8 qf0 = *(const bf16x8*)(qp + fr * HDIM + (fq << 3));
  const bf16x8 qf1 = *(const bf16x8*)(qp + fr * HDIM + 32 + (fq << 3));

  const unsigned short* Kg  = Kb  + ((size_t)(b * NKV + g)) * S_LEN * HDIM;  // [s][d]
  const unsigned short* Vtg = Vtb + ((size_t)(b * NKV + g)) * HDIM * S_LEN;  // [d][s]

  float l_part = 0.0f;          // per-lane denominator partial (q = fr)
  f32x4 o_acc[4] = {};

  int lo = q0 - (WIN - 1); if (lo < 0) lo = 0; lo &= ~63;
  const int hi = q0 + 64;
  const int full_lo = q0 - (WIN - 64);
  const int full_hi = q0 - 64;

  const unsigned short* src0;
  const unsigned short* src1;
  {
    const int x0 = ((w & 3) << 11) + (l << 4);
    const int x1 = x0 + 1024;
    if (w < 4) {
      const int s0 = x0 >> 7, o0 = ((x0 >> 4) & 7) ^ (s0 & 7);
      const int s1 = x1 >> 7, o1 = ((x1 >> 4) & 7) ^ (s1 & 7);
      const int p0 = ((s0 >> 5) << 5) | (((s0 >> 2) & 3) << 3) | (((s0 >> 4) & 1) << 2) | (s0 & 3);
      const int p1 = ((s1 >> 5) << 5) | (((s1 >> 2) & 3) << 3) | (((s1 >> 4) & 1) << 2) | (s1 & 3);
      src0 = Kg + (size_t)(lo + p0) * HDIM + (o0 << 3);
      src1 = Kg + (size_t)(lo + p1) * HDIM + (o1 << 3);
    } else {
      const int d0 = x0 >> 7, o0 = ((x0 >> 4) & 7) ^ (d0 & 7);
      const int d1 = x1 >> 7, o1 = ((x1 >> 4) & 7) ^ (d1 & 7);
      src0 = Vtg + (size_t)d0 * S_LEN + lo + (o0 << 3);
      src1 = Vtg + (size_t)d1 * S_LEN + lo + (o1 << 3);
    }
  }
  const int sadv = (w < 4) ? 64 * HDIM : 64;
  const int dbase = ((w < 4) ? 0 : 8192) + ((w & 3) << 11) + (l << 4);

  char* bufA = lds;
  char* bufB = lds + 16384;

  GLDS16(src0, bufA + dbase);
  GLDS16(src1, bufA + dbase + 1024);
  src0 += sadv; src1 += sadv;

  const int iq = q0 + (qh << 4) + fr;
  const int swr = (fr & 7) << 4;

  auto TILE = [&](int kv0, const char* sK, const char* sV, bool MASKED)
      __attribute__((always_inline)) {
    bf16x8 kf[2][2];
#pragma unroll
    for (int ntg = 0; ntg < 2; ++ntg) {
      const int slot = (kh << 5) + (ntg << 4) + fr;
      kf[ntg][0] = *(const bf16x8*)(sK + (((slot << 7) + (fq << 4)) ^ swr));
      kf[ntg][1] = *(const bf16x8*)(sK + (((slot << 7) + ((fq + 4) << 4)) ^ swr));
    }
    __builtin_amdgcn_s_setprio(1);
    f32x4 sf[2];
#pragma unroll
    for (int ntg = 0; ntg < 2; ++ntg) {
      f32x4 z = {};
      z = __builtin_amdgcn_mfma_f32_16x16x32_bf16(kf[ntg][0], qf0, z, 0, 0, 0);
      z = __builtin_amdgcn_mfma_f32_16x16x32_bf16(kf[ntg][1], qf1, z, 0, 0, 0);
      sf[ntg] = z;
    }
    __builtin_amdgcn_s_setprio(0);
    if (MASKED) {
#pragma unroll
      for (int ntg = 0; ntg < 2; ++ntg)
#pragma unroll
        for (int r = 0; r < 4; ++r) {
          const int jk = kv0 + (kh << 5) + (fq << 3) + (ntg << 2) + r;
          if (jk > iq || jk <= iq - WIN) sf[ntg][r] = -1e30f;
        }
    }
    // ---- P = exp2(S) (fixed shift m=0); pack in-register as PV A-frag ----
    union { unsigned short us[8]; bf16x8 v; } pu;
    float lloc = 0.0f;
#pragma unroll
    for (int ntg = 0; ntg < 2; ++ntg)
#pragma unroll
      for (int r = 0; r < 4; ++r) {
        const float p = EXP2(sf[ntg][r]);
        lloc += p;
        pu.us[(ntg << 2) + r] = f2bf(p);
      }
    l_part += lloc;
    bf16x8 vf[4];
#pragma unroll
    for (int dt = 0; dt < 4; ++dt) {
      const int d = (dt << 4) + fr;
      vf[dt] = *(const bf16x8*)(sV + ((d << 7) + ((((kh << 2) + fq) ^ (fr & 7)) << 4)));
    }
    __builtin_amdgcn_s_setprio(1);
#pragma unroll
    for (int dt = 0; dt < 4; ++dt)
      o_acc[dt] = __builtin_amdgcn_mfma_f32_16x16x32_bf16(pu.v, vf[dt], o_acc[dt], 0, 0, 0);
    __builtin_amdgcn_s_setprio(0);
  };

  for (int kv0 = lo; kv0 < hi; kv0 += 64) {
    VMDRAIN();
    __syncthreads();
    if (kv0 + 64 < hi) {
      GLDS16(src0, bufB + dbase);
      GLDS16(src1, bufB + dbase + 1024);
      src0 += sadv; src1 += sadv;
    }
    const bool masked = (kv0 < full_lo) || (kv0 > full_hi);
    if (masked) TILE(kv0, bufA, bufA + 8192, true);
    else        TILE(kv0, bufA, bufA + 8192, false);
    char* tmp = bufA; bufA = bufB; bufB = tmp;
  }

  // ---- epilogue: reduce l over fq lanes; merge kh halves (pure add) ----
  float lsum = l_part;
  lsum += __shfl_xor(lsum, 16);
  lsum += __shfl_xor(lsum, 32);

  VMDRAIN();
  __syncthreads();   // staging done; reuse lds as merge scratch
  if (w < 4) {       // kh=0 publish (o, l)
    char* ob = lds + ((w & 3) << 12);
#pragma unroll
    for (int dt = 0; dt < 4; ++dt)
      *(f32x4*)(ob + (dt << 10) + (l << 4)) = o_acc[dt];
    if (fq == 0)
      *(float*)(lds + 16384 + ((w & 3) << 7) + (fr << 2)) = lsum;
  }
  __syncthreads();
  if (w >= 4) {      // kh=1 merge + write ctx
    const char* ob = lds + ((w & 3) << 12);
    const float l_p = *(const float*)(lds + 16384 + ((w & 3) << 7) + (fr << 2));
    const float inv = 1.0f / (lsum + l_p);
    float al[4];
#pragma unroll
    for (int r = 0; r < 4; ++r) al[r] = __shfl(inv, (fq << 2) + r, 16);
    unsigned short* cp = ctx + ((size_t)(b * S_LEN + q0 + (qh << 4))) * D_MODEL + h * HDIM;
#pragma unroll
    for (int dt = 0; dt < 4; ++dt) {
      const f32x4 op = *(const f32x4*)(ob + (dt << 10) + (l << 4));
#pragma unroll
      for (int r = 0; r < 4; ++r) {
        const float of = (o_acc[dt][r] + op[r]) * al[r];
        cp[(size_t)((fq << 2) + r) * D_MODEL + (dt << 4) + fr] = f2bf(of);
      }
    }
  }
}

// ---------- launch ----------
extern "C" void kernel_launch(void* const* d_in, const int* in_sizes, int n_in,
                              void* d_out, int out_size, void* d_ws, size_t ws_size,
                              hipStream_t stream)
{
  const float* x    = (const float*)d_in[0];
  const float* Wqkv = (const float*)d_in[1];
  const float* bqkv = (const float*)d_in[2];
  const float* Wout = (const float*)d_in[3];
  const float* bout = (const float*)d_in[4];
  float* out = (float*)d_out;

  char* ws = (char*)d_ws;
  if (ws_size < 62914560u) return;

  unsigned short* xb    = (unsigned short*)(ws);
  unsigned short* ctx   = xb;                                  // alias after gemm1
  unsigned short* wqkvb = (unsigned short*)(ws + 16777216);
  unsigned short* woutb = (unsigned short*)(ws + 29360128);
  unsigned short* Qs    = (unsigned short*)(ws + 37748736);
  unsigned short* Kbuf  = (unsigned short*)(ws + 54525952);
  unsigned short* Vtbuf = (unsigned short*)(ws + 58720256);    // [b][g][d][s]

  cvt3<<<2048, 256, 0, stream>>>(x, xb, MTOT * D_MODEL,
                                 Wqkv, wqkvb, QKV_N * D_MODEL,
                                 Wout, woutb, D_MODEL * D_MODEL);

  gemm_nt<0><<<dim3(QKV_N / 128, MTOT / 128), 256, 0, stream>>>(
      xb, wqkvb, bqkv, D_MODEL, QKV_N, Qs, Kbuf, Vtbuf, nullptr);

  attn_swin<<<dim3(S_LEN / 64, NH, 2), 512, 0, stream>>>(Qs, Kbuf, Vtbuf, ctx);

  gemm_nt<1><<<dim3(D_MODEL / 128, MTOT / 128), 256, 0, stream>>>(
      ctx, woutb, bout, D_MODEL, D_MODEL, nullptr, nullptr, nullptr, out);
}